// Round 7
// baseline (1451.422 us; speedup 1.0000x reference)
//
#include <hip/hip_runtime.h>
#include <hip/hip_bf16.h>
#include <hip/hip_fp16.h>
#include <cstdint>
#include <cstddef>

#define NN 100000
#define EE 1600000
#define GG 2048

#define NOCT 8
#define OCTW 12500                    // src rows per octant
#define SLICE_BYTES (OCTW * 256)      // 3.2 MB octant slice of H (< 4 MB L2/XCD)
#define NBLK 768                      // 3 blocks/CU -> all co-resident (LDS-limited)
#define NGRPT (NBLK * 16)             // 12288 16-lane groups
#define NSLOT 9                       // ceil(NN / NGRPT)
#define NBIN (NOCT * NGRPT)           // 98304 (octant, group) bins
#define BSTR 56                       // bin pad; lambda~17.3, P(>=56) ~ 1e-14
#define PFCH 33344                    // prefetch chunk/block (96 blocks per XCD)

constexpr int NB_EDGE = (EE + NN + 255) / 256;  // 6641
constexpr int NB_GEMM = NN / 16;                // 6250
constexpr int NB_OUT  = (GG + 255) / 256;       // 8

typedef float floatx4 __attribute__((ext_vector_type(4)));  // native vec for nt-store

__device__ __forceinline__ float lrelu(float v) { return v > 0.f ? v : 0.2f * v; }

__device__ __forceinline__ void nt_store4(const float4& v, float4* p) {
    floatx4 t; t.x = v.x; t.y = v.y; t.z = v.z; t.w = v.w;
    __builtin_nontemporal_store(t, (floatx4*)p);
}

// ---------------- shared GEMM body (layer GEMM + attention-logit epilogue) --
// One wave = 4 rows; x-row pointers wave-uniform (SGPR via readfirstlane).
// H/als/ald stores are nontemporal: single cross-XCD read downstream, keeping
// them out of this XCD's L2 reduces dirty-line snoop cost for the gather fills.
template <int FIN>
__device__ __forceinline__ void gemm_body(int bidx, const float* __restrict__ X,
                                          const float* __restrict__ W,
                                          const float* __restrict__ asrc,
                                          const float* __restrict__ adst,
                                          float* __restrict__ H,
                                          float* __restrict__ als,
                                          float* __restrict__ ald) {
    int j  = threadIdx.x & 63;
    int ty = threadIdx.x >> 6;
    int row = __builtin_amdgcn_readfirstlane(bidx * 16 + ty * 4);
    const float* x0 = X + (size_t)row * FIN;
    const float* x1 = x0 + FIN;
    const float* x2 = x1 + FIN;
    const float* x3 = x2 + FIN;
    float a0 = 0.f, a1 = 0.f, a2 = 0.f, a3 = 0.f;
#pragma unroll
    for (int k = 0; k < FIN; k += 4) {
        float4 xa = *(const float4*)(x0 + k);
        float4 xb = *(const float4*)(x1 + k);
        float4 xc = *(const float4*)(x2 + k);
        float4 xd = *(const float4*)(x3 + k);
        float w0 = W[(k + 0) * 64 + j];
        float w1 = W[(k + 1) * 64 + j];
        float w2 = W[(k + 2) * 64 + j];
        float w3 = W[(k + 3) * 64 + j];
        a0 += xa.x * w0 + xa.y * w1 + xa.z * w2 + xa.w * w3;
        a1 += xb.x * w0 + xb.y * w1 + xb.z * w2 + xb.w * w3;
        a2 += xc.x * w0 + xc.y * w1 + xc.z * w2 + xc.w * w3;
        a3 += xd.x * w0 + xd.y * w1 + xd.z * w2 + xd.w * w3;
    }
    __builtin_nontemporal_store(a0, &H[(size_t)(row + 0) * 64 + j]);
    __builtin_nontemporal_store(a1, &H[(size_t)(row + 1) * 64 + j]);
    __builtin_nontemporal_store(a2, &H[(size_t)(row + 2) * 64 + j]);
    __builtin_nontemporal_store(a3, &H[(size_t)(row + 3) * 64 + j]);
    float asj = asrc[j], adj = adst[j];
    float accs[4] = {a0, a1, a2, a3};
#pragma unroll
    for (int r = 0; r < 4; r++) {
        float vs = accs[r] * asj;
        float vd = accs[r] * adj;
#pragma unroll
        for (int off = 8; off > 0; off >>= 1) {
            vs += __shfl_xor(vs, off, 64);
            vd += __shfl_xor(vd, off, 64);
        }
        if ((j & 15) == 0) {
            int h = j >> 4;
            __builtin_nontemporal_store(vs, &als[(size_t)(row + r) * 4 + h]);
            __builtin_nontemporal_store(vd, &ald[(size_t)(row + r) * 4 + h]);
        }
    }
}

template <int FIN>
__global__ __launch_bounds__(256) void k_gemm(const float* __restrict__ X,
                                              const float* __restrict__ W,
                                              const float* __restrict__ asrc,
                                              const float* __restrict__ adst,
                                              float* __restrict__ H,
                                              float* __restrict__ als,
                                              float* __restrict__ ald) {
    gemm_body<FIN>(blockIdx.x, X, W, asrc, adst, H, als, ald);
}

// ---------------- single-pass (octant, dst-group) binned build --------------
// bin = src_octant * NGRPT + dst%NGRPT; entry = (src<<4) | slot (slot = dst/NGRPT,
// 0..8). Contiguity per bin is all the gather needs (softmax order-invariant),
// so ONE atomic pass places everything. Fused with layer-0 GEMM and out init.
__global__ __launch_bounds__(256) void k_build(const int* __restrict__ ei,
                                               int* __restrict__ cnt2,
                                               int* __restrict__ col2,
                                               int* __restrict__ ofc,
                                               int* __restrict__ ofl,
                                               const float* __restrict__ X,
                                               const float* __restrict__ W,
                                               const float* __restrict__ asrc,
                                               const float* __restrict__ adst,
                                               float* __restrict__ H,
                                               float* __restrict__ als,
                                               float* __restrict__ ald,
                                               const float* __restrict__ head_b,
                                               float* __restrict__ out) {
    int b = blockIdx.x;
    if (b < NB_EDGE) {
        int i = b * 256 + threadIdx.x;
        if (i < EE + NN) {
            int s, d;
            if (i < EE) { s = ei[i]; d = ei[EE + i]; } else { s = d = i - EE; }
            int p    = (int)((unsigned)s / OCTW);
            int gid  = (int)((unsigned)d % NGRPT);
            int slot = (int)((unsigned)d / NGRPT);
            int bin  = p * NGRPT + gid;
            int r = atomicAdd(&cnt2[bin], 1);
            int tag = (s << 4) | slot;
            if (r < BSTR) __builtin_nontemporal_store(tag, &col2[bin * BSTR + r]);
            else { int o = atomicAdd(ofc, 1); ofl[2 * o] = s; ofl[2 * o + 1] = d; }
        }
    } else if (b < NB_EDGE + NB_GEMM) {
        gemm_body<128>(b - NB_EDGE, X, W, asrc, adst, H, als, ald);
    } else {
        int gI = (b - NB_EDGE - NB_GEMM) * 256 + threadIdx.x;
        if (gI < GG) out[gI] = head_b[0];
    }
}

// ---------------- octant-phased gather v2 ------------------------------------
// 768 persistent blocks (3/CU, co-resident). 8 phases, one src-octant each:
//   soft barrier (bounded spin, locality-only, deadlock-free)
//   -> sequential slice prefetch (fills this XCD's L2 at streaming rate)
//   -> FLAT 8-deep gather over this group's single contiguous bin run
//      (round-2's proven MLP structure), slot-tagged entries accumulated
//      into LDS per-slot accumulators (dynamic slot index is LDS-safe).
// Per-phase hot set: 3.2 MB H slice + 200 KB als slice (src in octant p!)
// fits the 4 MB per-XCD L2 -> demand loads hit L2 / merge with fills.
__global__ __launch_bounds__(256, 3) void k_aggph(
    const float* __restrict__ H, const float* __restrict__ als,
    const float* __restrict__ ald, const int* __restrict__ cnt2,
    const int* __restrict__ col2, const int* __restrict__ ofc,
    const int* __restrict__ ofl, const float* __restrict__ bias,
    const int* __restrict__ batch, const float* __restrict__ hw,
    float* __restrict__ out, float* __restrict__ Hout,
    int* __restrict__ ctr, int last) {
    __shared__ float4 accs[16 * NSLOT * 16];   // [g][slot][lane] 36.9 KB
    __shared__ float  ssums[16 * NSLOT * 16];  //                 9.2 KB
    __shared__ float  adhs[16 * NSLOT * 4];    // [g][slot][hsel] 2.3 KB
    int tid = threadIdx.x, b = blockIdx.x;
    int g = tid >> 4, l = tid & 15, hsel = l >> 2;
    int gid = b * 16 + g;
    int rid = b >> 3;                 // rank among this XCD's 96 blocks (b&7=XCD heuristic)
    const float4* Hp = (const float4*)H + l;

    for (int k = tid; k < 16 * NSLOT * 16; k += 256) {
        accs[k] = make_float4(0.f, 0.f, 0.f, 0.f);
        ssums[k] = 0.f;
    }
    for (int k = tid; k < 16 * NSLOT * 4; k += 256) {
        int g2 = k / (NSLOT * 4), r = k % (NSLOT * 4), t2 = r >> 2, h2 = r & 3;
        int n2 = (b * 16 + g2) + t2 * NGRPT;
        adhs[k] = (n2 < NN) ? ald[(size_t)n2 * 4 + h2] : 0.f;
    }
    __syncthreads();

    for (int p = 0; p < NOCT; p++) {
        // soft barrier: align all blocks on octant p (bounded spin)
        __syncthreads();
        if (tid == 0) {
            __hip_atomic_fetch_add(&ctr[p], 1, __ATOMIC_RELAXED, __HIP_MEMORY_SCOPE_AGENT);
            int polls = 0;
            while (polls++ < 64 &&
                   __hip_atomic_load(&ctr[p], __ATOMIC_RELAXED, __HIP_MEMORY_SCOPE_AGENT) < NBLK)
                __builtin_amdgcn_s_sleep(1);
        }
        __syncthreads();

        // sequential slice prefetch (one 4B touch per 64B line)
        {
            const char* sb = (const char*)H + (size_t)p * SLICE_BYTES + (size_t)rid * PFCH;
            float sink = 0.f;
#pragma unroll
            for (int k = 0; k < 3; k++) {
                int off = (tid + k * 256) * 64;
                if (off < PFCH && (size_t)rid * PFCH + off < SLICE_BYTES)
                    sink += *(const float*)(sb + off);
            }
            asm volatile("" :: "v"(sink));
        }

        // flat 8-deep gather over this group's bin run
        int bin = p * NGRPT + gid;
        int cnt = cnt2[bin];
        int c = cnt < BSTR ? cnt : BSTR;
        int base = bin * BSTR;
        for (int e = 0; e < c; e += 8) {
            bool v[8]; int tg[8];
#pragma unroll
            for (int i = 0; i < 8; i++) {
                v[i] = (e + i < c);
                tg[i] = v[i] ? col2[base + e + i] : 0;
            }
            float w[8]; float4 hr[8]; int ti[8];
#pragma unroll
            for (int i = 0; i < 8; i++) {
                int s = tg[i] >> 4;
                ti[i] = tg[i] & 15;
                float a = als[(size_t)s * 4 + hsel];
                hr[i] = Hp[(size_t)s * 16];
                float ad = adhs[(g * NSLOT + ti[i]) * 4 + hsel];
                w[i] = v[i] ? __expf(lrelu(a + ad)) : 0.f;
            }
#pragma unroll
            for (int i = 0; i < 8; i++) {
                int idx = (g * NSLOT + ti[i]) * 16 + l;
                float4 a4 = accs[idx];
                a4.x = fmaf(w[i], hr[i].x, a4.x);
                a4.y = fmaf(w[i], hr[i].y, a4.y);
                a4.z = fmaf(w[i], hr[i].z, a4.z);
                a4.w = fmaf(w[i], hr[i].w, a4.w);
                accs[idx] = a4;
                ssums[idx] += w[i];
            }
        }
    }
    __syncthreads();

    // overflow fallback (empty in practice; correctness only)
    int oc = *ofc;
    if (oc > 0) {
        for (int k = 0; k < oc; k++) {
            int s = ofl[2 * k], d = ofl[2 * k + 1];
            if ((int)((unsigned)d % NGRPT) == gid) {
                int t = (int)((unsigned)d / NGRPT);
                float a = als[(size_t)s * 4 + hsel];
                float4 h0 = Hp[(size_t)s * 16];
                float ad = adhs[(g * NSLOT + t) * 4 + hsel];
                float w0 = __expf(lrelu(a + ad));
                int idx = (g * NSLOT + t) * 16 + l;
                float4 a4 = accs[idx];
                a4.x = fmaf(w0, h0.x, a4.x); a4.y = fmaf(w0, h0.y, a4.y);
                a4.z = fmaf(w0, h0.z, a4.z); a4.w = fmaf(w0, h0.w, a4.w);
                accs[idx] = a4;
                ssums[idx] += w0;
            }
        }
    }

    // finalize: normalize + bias + relu; store rows or head-project + pool
    float4 b4 = ((const float4*)bias)[l];
    float4 w4 = make_float4(0.f, 0.f, 0.f, 0.f);
    if (last) w4 = ((const float4*)hw)[l];
#pragma unroll
    for (int t = 0; t < NSLOT; t++) {
        int n = gid + t * NGRPT;
        if (n < NN) {
            int idx = (g * NSLOT + t) * 16 + l;
            float4 a4 = accs[idx];
            float inv = 1.f / (ssums[idx] + 1e-16f);
            float4 o;
            o.x = fmaxf(a4.x * inv + b4.x, 0.f);
            o.y = fmaxf(a4.y * inv + b4.y, 0.f);
            o.z = fmaxf(a4.z * inv + b4.z, 0.f);
            o.w = fmaxf(a4.w * inv + b4.w, 0.f);
            if (!last) {
                nt_store4(o, &((float4*)Hout)[(size_t)n * 16 + l]);
            } else {
                float tt = o.x * w4.x + o.y * w4.y + o.z * w4.z + o.w * w4.w;
#pragma unroll
                for (int off = 8; off > 0; off >>= 1) tt += __shfl_xor(tt, off, 16);
                if (l == 0) atomicAdd(&out[batch[n]], tt);
            }
        }
    }
}

// ---------------- launch -----------------------------------------------------
extern "C" void kernel_launch(void* const* d_in, const int* in_sizes, int n_in,
                              void* d_out, int out_size, void* d_ws, size_t ws_size,
                              hipStream_t stream) {
    const float* x     = (const float*)d_in[0];
    const int*   ei    = (const int*)d_in[1];
    const int*   batch = (const int*)d_in[2];
    const float* Wm[3] = {(const float*)d_in[3], (const float*)d_in[7],  (const float*)d_in[11]};
    const float* As[3] = {(const float*)d_in[4], (const float*)d_in[8],  (const float*)d_in[12]};
    const float* Ad[3] = {(const float*)d_in[5], (const float*)d_in[9],  (const float*)d_in[13]};
    const float* Bb[3] = {(const float*)d_in[6], (const float*)d_in[10], (const float*)d_in[14]};
    const float* hw = (const float*)d_in[15];
    const float* hb = (const float*)d_in[16];
    float* out = (float*)d_out;

    uint8_t* w = (uint8_t*)d_ws;
    auto alloc = [&](size_t bytes) -> void* {
        void* p = (void*)w;
        w += (bytes + 255) & ~(size_t)255;
        return p;
    };
    float* H    = (float*)alloc((size_t)NN * 64 * 4);        // ping (gather source)
    float* Bf   = (float*)alloc((size_t)NN * 64 * 4);        // pong
    float* als  = (float*)alloc((size_t)NN * 4 * 4);
    float* ald  = (float*)alloc((size_t)NN * 4 * 4);
    int*   meta = (int*)alloc((size_t)(NBIN + 64) * 4);      // cnt2 + ofc + ctr
    int*   col2 = (int*)alloc((size_t)NBIN * BSTR * 4);      // 22 MB binned CSR
    int*   ofl  = (int*)alloc((size_t)4096 * 2 * 4);

    int* cnt2 = meta;
    int* ofc  = meta + NBIN;
    int* ctr  = ofc + 8;     // 24 phase counters (3 layers x 8)

    hipMemsetAsync(meta, 0, (size_t)(NBIN + 64) * 4, stream);

    // binned build || layer-0 GEMM || out init, one grid
    k_build<<<NB_EDGE + NB_GEMM + NB_OUT, 256, 0, stream>>>(
        ei, cnt2, col2, ofc, ofl,
        x, Wm[0], As[0], Ad[0], H, als, ald, hb, out);

    // layer 0
    k_aggph<<<NBLK, 256, 0, stream>>>(H, als, ald, cnt2, col2, ofc, ofl, Bb[0],
                                      batch, hw, out, Bf, ctr + 0, 0);
    // layer 1
    k_gemm<64><<<NB_GEMM, 256, 0, stream>>>(Bf, Wm[1], As[1], Ad[1], H, als, ald);
    k_aggph<<<NBLK, 256, 0, stream>>>(H, als, ald, cnt2, col2, ofc, ofl, Bb[1],
                                      batch, hw, out, Bf, ctr + 8, 0);
    // layer 2
    k_gemm<64><<<NB_GEMM, 256, 0, stream>>>(Bf, Wm[2], As[2], Ad[2], H, als, ald);
    k_aggph<<<NBLK, 256, 0, stream>>>(H, als, ald, cnt2, col2, ofc, ofl, Bb[2],
                                      batch, hw, out, H /*unused*/, ctr + 16, 1);
}